// Round 4
// 198.287 us; speedup vs baseline: 1.0503x; 1.0503x over previous
//
#include <hip/hip_runtime.h>
#include <math.h>

#define TMAX 16384
#define MDIM 16
#define SD   2048
#define CHK  512     // number of parallel chunks
#define CLEN 32      // steps per chunk (CHK*CLEN == TMAX)
#define WUP  32      // warmup steps per chunk (boundary forgetting)
#define EROWS 32     // t-rows per emP block

typedef unsigned int  uint;
typedef unsigned short ushort;
typedef __attribute__((ext_vector_type(8))) short short8;
typedef __attribute__((ext_vector_type(4))) short short4v;
typedef __attribute__((ext_vector_type(4))) float floatx4;
typedef __attribute__((ext_vector_type(2))) uint uintx2;

// ---- DPP-based full-wave (64-lane) max ----
template<int CTRL>
__device__ __forceinline__ float fmax_dpp(float v) {
    int o = __builtin_amdgcn_update_dpp(__float_as_int(v), __float_as_int(v),
                                        CTRL, 0xf, 0xf, false);
    return fmaxf(v, __int_as_float(o));
}
__device__ __forceinline__ float waveMax64(float v) {
    v = fmax_dpp<0x111>(v);
    v = fmax_dpp<0x112>(v);
    v = fmax_dpp<0x114>(v);
    v = fmax_dpp<0x118>(v);
    v = fmax_dpp<0x142>(v);
    v = fmax_dpp<0x143>(v);
    return __int_as_float(__builtin_amdgcn_readlane(__float_as_int(v), 63));
}
__device__ __forceinline__ float waveSumF(float v) {
    #pragma unroll
    for (int o = 32; o > 0; o >>= 1) v += __shfl_xor(v, o, 64);
    return v;
}
__device__ __forceinline__ double waveSumD(double v) {
    #pragma unroll
    for (int o = 32; o > 0; o >>= 1) v += __shfl_xor(v, o, 64);
    return v;
}

// bf16 helpers (RNE emulation — bit-exact, harness-proven; cvt_pk asm reverted
// after it produced NaN cascade in R3)
__device__ __forceinline__ short f2bfs(float f) {
    uint u = __float_as_uint(f);
    return (short)((u + 0x7FFFu + ((u >> 16) & 1u)) >> 16);
}
__device__ __forceinline__ uint pkbf(float a, float b) {
    uint ua = __float_as_uint(a), ub = __float_as_uint(b);
    ua = (ua + 0x7FFFu + ((ua >> 16) & 1u)) >> 16;
    ub = (ub + 0x7FFFu + ((ub >> 16) & 1u)) & 0xFFFF0000u;
    return ua | ub;
}
__device__ __forceinline__ short4v pk4(float a, float b, float c, float d) {
    short4v r;
    r[0] = f2bfs(a); r[1] = f2bfs(b); r[2] = f2bfs(c); r[3] = f2bfs(d);
    return r;
}
__device__ __forceinline__ float bfl(uint u) { return __uint_as_float(u << 16); }
__device__ __forceinline__ float bfh(uint u) { return __uint_as_float(u & 0xFFFF0000u); }

// K=16 bf16 MFMA
#if __has_builtin(__builtin_amdgcn_mfma_f32_16x16x16bf16_1k)
#define MFMA16(a, b, c) __builtin_amdgcn_mfma_f32_16x16x16bf16_1k(a, b, c, 0, 0, 0)
#else
__device__ __forceinline__ floatx4 mfma16_asm(short4v a, short4v b, floatx4 c) {
    asm volatile("v_mfma_f32_16x16x16_bf16 %0, %1, %2, %0\n\t"
                 "s_nop 7\n\ts_nop 7"
                 : "+v"(c) : "v"(a), "v"(b));
    return c;
}
#define MFMA16(a, b, c) mfma16_asm(a, b, c)
#endif
#define MFMA32(a, b, c) __builtin_amdgcn_mfma_f32_16x16x32_bf16(a, b, c, 0, 0, 0)

// ---- K2: fused pre-pass. 512 blocks x 512 threads x 32 t-rows each.
// 4 states/thread (llc = 64 VGPR -> 2 blocks/CU), one barrier per row.
// Slot order identical to baseline: slot o = tid*4 + j ->
// s = (4q+j)*128 + 16*wv + nn  (q=lane>>4, nn=lane&15, wv=tid>>6).
__global__ __launch_bounds__(512, 4)
void emP_kernel(const int* __restrict__ x,
                const float* __restrict__ lam1,
                const float* __restrict__ lam2,
                const float* __restrict__ lam3,
                ushort* __restrict__ P,
                float* __restrict__ SumAux) {
    __shared__ __align__(16) float red[2][8];
    __shared__ float lgtbl[32];
    __shared__ float lgred;
    const int tid = threadIdx.x, lane = tid & 63, wv = tid >> 6;
    const int q = lane >> 4, nn = lane & 15;
    const int d2 = 2 * wv + (nn >> 3);
    const int d3 = nn & 7;

    if (tid < 32) lgtbl[tid] = lgammaf((float)tid + 1.0f);
    if (tid == 0) lgred = 0.f;

    float llc[4][16], ls[4];
    #pragma unroll
    for (int j = 0; j < 4; ++j) {
        const int d1 = 4 * q + j;
        float sum = 0.f;
        #pragma unroll
        for (int m = 0; m < 16; ++m) {
            float la = lam1[d1 * 16 + m] + lam2[d2 * 16 + m] + lam3[d3 * 16 + m];
            sum += la;
            llc[j][m] = __logf(la);
        }
        ls[j] = sum;
    }
    __syncthreads();   // lgtbl + lgred ready

    const int t0 = blockIdx.x * EROWS;
    // lgamma over this block's 32 t-rows (512 ints): 1 per thread
    {
        int v = x[t0 * MDIM + tid];
        double lg = (double)lgtbl[v & 31];
        lg = waveSumD(lg);
        if (lane == 0) atomicAdd(&lgred, (float)lg);
    }

    double sumD = 0.0;
    for (int ti = 0; ti < EROWS; ++ti) {
        const int t = t0 + ti;
        const int* __restrict__ xr = x + t * MDIM;   // uniform -> scalar loads
        float em[4];
        float vm = -3.4e38f;
        #pragma unroll
        for (int j = 0; j < 4; ++j) {
            float d = 0.f;
            #pragma unroll
            for (int m = 0; m < 16; ++m) d = fmaf((float)xr[m], llc[j][m], d);
            em[j] = d - ls[j];
            vm = fmaxf(vm, em[j]);
        }
        vm = waveMax64(vm);
        if (lane == 0) red[ti & 1][wv] = vm;
        __syncthreads();               // single barrier/row (red double-buffered)
        const float4 ra = *(const float4*)&red[ti & 1][0];
        const float4 rb = *(const float4*)&red[ti & 1][4];
        float Dem = fmaxf(fmaxf(fmaxf(ra.x, ra.y), fmaxf(ra.z, ra.w)),
                          fmaxf(fmaxf(rb.x, rb.y), fmaxf(rb.z, rb.w)));
        uint2 w;
        w.x = pkbf(__expf(em[0] - Dem), __expf(em[1] - Dem));
        w.y = pkbf(__expf(em[2] - Dem), __expf(em[3] - Dem));
        *(uint2*)(P + (size_t)t * SD + tid * 4) = w;
        if (tid == 0) sumD += (double)Dem;
    }
    __syncthreads();
    if (tid == 0) atomicAdd(SumAux, (float)sumD - lgred);
}

// ---- K3: CHUNKED forward recurrence. grid = CHK blocks x 512 threads.
// Defer-rescale every 2 steps: odd steps compute per-wave max only (wa -> wmA);
// even steps apply inv = 1/max(beta_{t-1}) and accumulate log when t > bAcc.
// Exact-telescoping proof: with defer, C_t (applied scale) = max(beta'_{t-3})
// through each even/odd pair; logged terms telescope over the odd-index chain
// to G = log[max beta'_{tEnd-1}/max beta'_{bAcc-1}] — identical to every-step
// rescale. Range-safe: per-step shrink >= e^{-48} >> f32 min normal.
__global__ __launch_bounds__(512, 2)
void fhmm_chunk_kernel(const ushort* __restrict__ P,
                       const float* __restrict__ SumAux,
                       const float* __restrict__ logA1,
                       const float* __restrict__ logA2,
                       const float* __restrict__ logA3,
                       const float* __restrict__ logpi1,
                       const float* __restrict__ logpi2,
                       const float* __restrict__ logpi3,
                       float* __restrict__ out)
{
    __shared__ __align__(16) short c1b[2 * 2048];   // parity double buffer
    __shared__ float wmA[8];                        // odd steps write, even read
    __shared__ float sred[8];

    const int tid  = threadIdx.x;
    const int lane = tid & 63;
    const int wv   = tid >> 6;
    const int q    = lane >> 4;
    const int ml   = lane & 15;

    const int c    = blockIdx.x;
    const int tw0  = (c == 0) ? 0 : c * CLEN - WUP;
    const int tEnd = (c + 1) * CLEN;
    const int bAcc = c * CLEN;

    // S1 constants (K=16): B[k=p1=4q+j][n=d1'=ml] = exp(logA1[ml][4q+j])
    short4v bA1k;
    #pragma unroll
    for (int j = 0; j < 4; ++j)
        bA1k[j] = f2bfs(__expf(logA1[ml * 16 + 4 * q + j]));

    // S23 constants, 4 K-chunks: k' = 32jc + 8q + i -> p2 = 4jc+q, p3 = i
    const int d2p = 2 * wv + (ml >> 3);
    const int d3p = ml & 7;
    short8 bK[4];
    #pragma unroll
    for (int jc = 0; jc < 4; ++jc)
        #pragma unroll
        for (int i = 0; i < 8; ++i)
            bK[jc][i] = f2bfs(__expf(logA2[d2p * 16 + 4 * jc + q] + logA3[d3p * 8 + i]));

    // S1 D write offset into c1b[par]  [R9/R10-verified]
    const int oS1w = ml * 128 + ((((2 * wv + (q >> 1)) ^ ml) & 15) << 3) + 4 * (q & 1);
    // S23 A-frag offsets [R9/R10-verified]
    int o23[4];
    #pragma unroll
    for (int jc = 0; jc < 4; ++jc)
        o23[jc] = ml * 128 + ((((4 * jc + q) ^ ml) & 15) << 3);

    // ---- init beta at t = tw0 ----
    double OFF = 0.0;
    float nu0, nu1, nu2, nu3;
    {
        uintx2 p0 = *(const uintx2*)(P + (size_t)tw0 * SD + tid * 4);
        if (c == 0) {   // exact: beta_0 = P_0 * pi
            float lp23 = logpi2[d2p] + logpi3[d3p];
            nu0 = bfl(p0.x) * __expf(logpi1[4 * q + 0] + lp23);
            nu1 = bfh(p0.x) * __expf(logpi1[4 * q + 1] + lp23);
            nu2 = bfl(p0.y) * __expf(logpi1[4 * q + 2] + lp23);
            nu3 = bfh(p0.y) * __expf(logpi1[4 * q + 3] + lp23);
        } else {        // warm-start: beta = P row (arbitrary positive scale)
            nu0 = bfl(p0.x); nu1 = bfh(p0.x);
            nu2 = bfl(p0.y); nu3 = bfh(p0.y);
        }
    }

    // 2-deep P prefetch
    uintx2 Pb0 = *(const uintx2*)(P + (size_t)(tw0 + 1) * SD + tid * 4);
    uintx2 Pb1 = *(const uintx2*)(P + (size_t)(tw0 + 2) * SD + tid * 4);

// One forward step. RESC: compile-time (apply inv + maybe log); on !RESC steps
// compute the per-wave max (wa) feeding the next RESC step. ACCF: runtime
// uniform bool (t > bAcc) gating OFF accumulation.
#define FSTEP(T, RESC, ACCF)                                                    \
{                                                                               \
    const int par = (T) & 1;                                                    \
    short* c1cur = c1b + (par << 11);                                           \
    {   /* Stage 1 from registers */                                            \
        short4v af = pk4(nu0, nu1, nu2, nu3);                                   \
        floatx4 s1 = {0.f, 0.f, 0.f, 0.f};                                      \
        s1 = MFMA16(af, bA1k, s1);                                              \
        ((uintx2*)(c1cur + oS1w))[0] =                                          \
            (uintx2){pkbf(s1[0], s1[1]), pkbf(s1[2], s1[3])};                   \
    }                                                                           \
    __syncthreads();                                                            \
    const int tn = ((T) + 2 < TMAX) ? (T) + 2 : TMAX - 1;                       \
    uintx2 Pb2 = *(const uintx2*)(P + (size_t)tn * SD + tid * 4);               \
    float inv = 1.f;                                                            \
    if (RESC) {                                                                 \
        float mp = waveMax64(wmA[lane & 7]);                                    \
        float mg = fmaxf(mp, 1e-30f);                                           \
        inv = __builtin_amdgcn_rcpf(mg);                                        \
        if ((ACCF) && tid == 0) OFF += (double)__logf(mg);                      \
    }                                                                           \
    {   /* Stage 2+3 fused */                                                   \
        floatx4 a0 = {0.f, 0.f, 0.f, 0.f};                                      \
        floatx4 a1 = {0.f, 0.f, 0.f, 0.f};                                      \
        a0 = MFMA32(*(const short8*)(c1cur + o23[0]), bK[0], a0);               \
        a1 = MFMA32(*(const short8*)(c1cur + o23[1]), bK[1], a1);               \
        a0 = MFMA32(*(const short8*)(c1cur + o23[2]), bK[2], a0);               \
        a1 = MFMA32(*(const short8*)(c1cur + o23[3]), bK[3], a1);               \
        floatx4 acc = a0 + a1;                                                  \
        if (RESC) {                                                             \
            nu0 = bfl(Pb0.x) * acc[0] * inv;                                    \
            nu1 = bfh(Pb0.x) * acc[1] * inv;                                    \
            nu2 = bfl(Pb0.y) * acc[2] * inv;                                    \
            nu3 = bfh(Pb0.y) * acc[3] * inv;                                    \
        } else {                                                                \
            nu0 = bfl(Pb0.x) * acc[0];                                          \
            nu1 = bfh(Pb0.x) * acc[1];                                          \
            nu2 = bfl(Pb0.y) * acc[2];                                          \
            nu3 = bfh(Pb0.y) * acc[3];                                          \
            float wa = waveMax64(fmaxf(fmaxf(nu0, nu1), fmaxf(nu2, nu3)));      \
            if (lane == 0) wmA[wv] = wa;                                        \
        }                                                                       \
    }                                                                           \
    Pb0 = Pb1; Pb1 = Pb2;                                                       \
}

    // steps tw0+1 .. tEnd-1; first and last are odd (tw0, tEnd, bAcc all even)
    FSTEP(tw0 + 1, false, false);
    for (int te = tw0 + 2; te < tEnd; te += 2) {
        const bool accf = te > bAcc;
        FSTEP(te, true, accf);
        FSTEP(te + 1, false, false);
    }
#undef FSTEP

    __syncthreads();

    if (c == CHK - 1) {
        float su = waveSumF(nu0 + nu1 + nu2 + nu3);
        if (lane == 0) sred[wv] = su;
        __syncthreads();
        if (tid == 0) {
            float tot = 0.f;
            #pragma unroll
            for (int i = 0; i < 8; ++i) tot += sred[i];
            OFF += (double)__logf(tot);
            atomicAdd(out, (float)OFF);
        }
    } else {
        if (tid == 0) {
            float mp = wmA[0];
            #pragma unroll
            for (int i = 1; i < 8; ++i) mp = fmaxf(mp, wmA[i]);
            OFF += (double)__logf(fmaxf(mp, 1e-30f));
            if (c == 0) OFF += (double)SumAux[0];
            atomicAdd(out, (float)OFF);
        }
    }
}

extern "C" void kernel_launch(void* const* d_in, const int* in_sizes, int n_in,
                              void* d_out, int out_size, void* d_ws, size_t ws_size,
                              hipStream_t stream) {
    const int*   x      = (const int*)  d_in[0];
    const float* lam1   = (const float*)d_in[1];
    const float* lam2   = (const float*)d_in[2];
    const float* lam3   = (const float*)d_in[3];
    const float* logA1  = (const float*)d_in[4];
    const float* logA2  = (const float*)d_in[5];
    const float* logA3  = (const float*)d_in[6];
    const float* logpi1 = (const float*)d_in[7];
    const float* logpi2 = (const float*)d_in[8];
    const float* logpi3 = (const float*)d_in[9];
    float* out = (float*)d_out;

    // ws: [SumAux (256B)] [P_perm: TMAX*2048*2B = 64MB]
    float*  SumAux = (float*)d_ws;
    ushort* P      = (ushort*)((char*)d_ws + 256);

    hipMemsetAsync(out, 0, sizeof(float), stream);
    hipMemsetAsync(SumAux, 0, sizeof(float), stream);
    emP_kernel <<<dim3(TMAX / EROWS), dim3(512), 0, stream>>>(x, lam1, lam2, lam3, P, SumAux);
    fhmm_chunk_kernel<<<dim3(CHK), dim3(512), 0, stream>>>(
        P, SumAux, logA1, logA2, logA3, logpi1, logpi2, logpi3, out);
}